// Round 1
// baseline (1134.145 us; speedup 1.0000x reference)
//
#include <hip/hip_runtime.h>

#define D0 128
#define D1 128
#define D2 96
#define VOL (D0 * D1 * D2)

// Counters: [0]=|bp| [1]=|bg| [2]=ov_p [3]=ov_g
__global__ void zero_counters(unsigned int* c) {
    if (threadIdx.x < 4) c[threadIdx.x] = 0u;
}

// Pass 1: per-voxel boundary masks. bit0 = bp (pred boundary), bit1 = bg (gt boundary).
__global__ void boundary_kernel(const float* __restrict__ net,
                                const int* __restrict__ tgt,
                                unsigned char* __restrict__ b) {
    int idx = blockIdx.x * blockDim.x + threadIdx.x;
    if (idx >= VOL) return;
    int z = idx % D2;
    int y = (idx / D2) % D1;
    int x = idx / (D1 * D2);

    bool p = net[idx] > 0.0f;   // sigmoid(v) > 0.5  <=>  v > 0
    bool g = tgt[idx] != 0;

    unsigned char out = 0;
    if (p | g) {
        bool ip = true, ig = true;  // interior flags (all 6 neighbors foreground)
#define NB(cond, ni)                                   \
        {                                              \
            bool np = false, ng = false;               \
            if (cond) {                                \
                int nn = (ni);                         \
                np = net[nn] > 0.0f;                   \
                ng = tgt[nn] != 0;                     \
            }                                          \
            ip &= np;                                  \
            ig &= ng;                                  \
        }
        NB(x > 0,        idx - D1 * D2);
        NB(x < D0 - 1,   idx + D1 * D2);
        NB(y > 0,        idx - D2);
        NB(y < D1 - 1,   idx + D2);
        NB(z > 0,        idx - 1);
        NB(z < D2 - 1,   idx + 1);
#undef NB
        out = (unsigned char)(((p && !ip) ? 1 : 0) | ((g && !ig) ? 2 : 0));
    }
    b[idx] = out;
}

// Pass 2: d2<=1 test == 7-point-cross dilation of the other boundary set.
__global__ void count_kernel(const unsigned char* __restrict__ b,
                             unsigned int* __restrict__ cnt) {
    int idx = blockIdx.x * blockDim.x + threadIdx.x;
    bool bp = false, bg = false, ovp = false, ovg = false;
    if (idx < VOL) {
        unsigned char c = b[idx];
        bp = (c & 1) != 0;
        bg = (c & 2) != 0;
        if (c) {
            int z = idx % D2;
            int y = (idx / D2) % D1;
            int x = idx / (D1 * D2);
            unsigned char o = c;
            if (x > 0)      o |= b[idx - D1 * D2];
            if (x < D0 - 1) o |= b[idx + D1 * D2];
            if (y > 0)      o |= b[idx - D2];
            if (y < D1 - 1) o |= b[idx + D2];
            if (z > 0)      o |= b[idx - 1];
            if (z < D2 - 1) o |= b[idx + 1];
            ovp = bp && ((o & 2) != 0);   // bp voxel within distance 1 of bg
            ovg = bg && ((o & 1) != 0);   // bg voxel within distance 1 of bp
        }
    }
    // wave64 reduce via ballot+popcount, one atomic per wave per counter
    unsigned int nbp  = (unsigned int)__popcll(__ballot(bp));
    unsigned int nbg  = (unsigned int)__popcll(__ballot(bg));
    unsigned int novp = (unsigned int)__popcll(__ballot(ovp));
    unsigned int novg = (unsigned int)__popcll(__ballot(ovg));
    if ((threadIdx.x & 63) == 0) {
        if (nbp)  atomicAdd(&cnt[0], nbp);
        if (nbg)  atomicAdd(&cnt[1], nbg);
        if (novp) atomicAdd(&cnt[2], novp);
        if (novg) atomicAdd(&cnt[3], novg);
    }
}

__global__ void finalize_kernel(const unsigned int* __restrict__ cnt,
                                float* __restrict__ out) {
    if (threadIdx.x == 0 && blockIdx.x == 0) {
        float denom = (float)(cnt[0] + cnt[1]);
        float num   = (float)(cnt[2] + cnt[3]);
        out[0] = denom > 0.0f ? num / denom : 0.0f;
    }
}

extern "C" void kernel_launch(void* const* d_in, const int* in_sizes, int n_in,
                              void* d_out, int out_size, void* d_ws, size_t ws_size,
                              hipStream_t stream) {
    const float* net = (const float*)d_in[0];
    const int*   tgt = (const int*)d_in[1];
    float* out = (float*)d_out;

    unsigned char* bmask = (unsigned char*)d_ws;
    unsigned int*  cnt   = (unsigned int*)((char*)d_ws + VOL);  // VOL is 4-aligned

    const int threads = 256;
    const int blocks  = (VOL + threads - 1) / threads;

    zero_counters<<<1, 64, 0, stream>>>(cnt);
    boundary_kernel<<<blocks, threads, 0, stream>>>(net, tgt, bmask);
    count_kernel<<<blocks, threads, 0, stream>>>(bmask, cnt);
    finalize_kernel<<<1, 64, 0, stream>>>(cnt, out);
}

// Round 2
// 23.200 us; speedup vs baseline: 48.8858x; 48.8858x over previous
//
#include <hip/hip_runtime.h>

#define D0 128
#define D1 128
#define D2 96
#define VOL (D0 * D1 * D2)
#define NBLK 2048   // fixed grid for count_kernel (grid-stride)

// Pass 1: per-voxel boundary masks. bit0 = bp (pred boundary), bit1 = bg (gt boundary).
__global__ void boundary_kernel(const float* __restrict__ net,
                                const int* __restrict__ tgt,
                                unsigned char* __restrict__ b) {
    int idx = blockIdx.x * blockDim.x + threadIdx.x;
    if (idx >= VOL) return;
    int z = idx % D2;
    int y = (idx / D2) % D1;
    int x = idx / (D1 * D2);

    bool p = net[idx] > 0.0f;   // sigmoid(v) > 0.5  <=>  v > 0
    bool g = tgt[idx] != 0;

    unsigned char out = 0;
    if (p | g) {
        bool ip = true, ig = true;  // interior flags (all 6 neighbors foreground)
#define NB(cond, ni)                                   \
        {                                              \
            bool np = false, ng = false;               \
            if (cond) {                                \
                int nn = (ni);                         \
                np = net[nn] > 0.0f;                   \
                ng = tgt[nn] != 0;                     \
            }                                          \
            ip &= np;                                  \
            ig &= ng;                                  \
        }
        NB(x > 0,        idx - D1 * D2);
        NB(x < D0 - 1,   idx + D1 * D2);
        NB(y > 0,        idx - D2);
        NB(y < D1 - 1,   idx + D2);
        NB(z > 0,        idx - 1);
        NB(z < D2 - 1,   idx + 1);
#undef NB
        out = (unsigned char)(((p && !ip) ? 1 : 0) | ((g && !ig) ? 2 : 0));
    }
    b[idx] = out;
}

// Pass 2: d2<=1 test == 7-point-cross dilation of the other boundary set.
// No global atomics: per-thread packed u64 counts -> wave shuffle reduce ->
// LDS block reduce -> one uint4 partial per block.
__global__ void count_kernel(const unsigned char* __restrict__ b,
                             uint4* __restrict__ partials) {
    // packed fields: [0:16)=ovp [16:32)=ovg [32:48)=bp [48:64)=bg
    unsigned long long acc = 0ull;
    const int stride = NBLK * 256;
    for (int idx = blockIdx.x * 256 + threadIdx.x; idx < VOL; idx += stride) {
        unsigned char c = b[idx];
        if (!c) continue;
        bool bp = (c & 1) != 0;
        bool bg = (c & 2) != 0;
        int z = idx % D2;
        int y = (idx / D2) % D1;
        int x = idx / (D1 * D2);
        unsigned char o = c;
        if (x > 0)      o |= b[idx - D1 * D2];
        if (x < D0 - 1) o |= b[idx + D1 * D2];
        if (y > 0)      o |= b[idx - D2];
        if (y < D1 - 1) o |= b[idx + D2];
        if (z > 0)      o |= b[idx - 1];
        if (z < D2 - 1) o |= b[idx + 1];
        bool ovp = bp && ((o & 2) != 0);
        bool ovg = bg && ((o & 1) != 0);
        acc += (unsigned long long)(ovp ? 1u : 0u)
             + ((unsigned long long)(ovg ? 1u : 0u) << 16)
             + ((unsigned long long)(bp  ? 1u : 0u) << 32)
             + ((unsigned long long)(bg  ? 1u : 0u) << 48);
    }
    // wave64 reduce (fields max 64*8=512 < 65536, no cross-field carry)
    #pragma unroll
    for (int off = 32; off >= 1; off >>= 1)
        acc += __shfl_down(acc, off, 64);

    __shared__ unsigned long long wsum[4];
    int wave = threadIdx.x >> 6;
    if ((threadIdx.x & 63) == 0) wsum[wave] = acc;
    __syncthreads();
    if (threadIdx.x == 0) {
        unsigned long long t = wsum[0] + wsum[1] + wsum[2] + wsum[3];
        uint4 r;
        r.x = (unsigned int)( t        & 0xFFFF);   // ovp
        r.y = (unsigned int)((t >> 16) & 0xFFFF);   // ovg
        r.z = (unsigned int)((t >> 32) & 0xFFFF);   // bp
        r.w = (unsigned int)((t >> 48) & 0xFFFF);   // bg
        partials[blockIdx.x] = r;
    }
}

__global__ void finalize_kernel(const uint4* __restrict__ partials,
                                float* __restrict__ out) {
    // one block, 256 threads; each sums NBLK/256 partials
    unsigned int ovp = 0, ovg = 0, bp = 0, bg = 0;
    for (int i = threadIdx.x; i < NBLK; i += 256) {
        uint4 v = partials[i];
        ovp += v.x; ovg += v.y; bp += v.z; bg += v.w;
    }
    unsigned long long acc = (unsigned long long)ovp
                           + ((unsigned long long)ovg << 16)
                           + ((unsigned long long)bp  << 32)
                           + ((unsigned long long)bg  << 48);
    // fields: per-thread sums <= 8 blocks * 2048 = 16384; wave sum <= 1.05M -> need
    // wider fields? bp total can reach ~780K which overflows 16 bits. Use LDS uint4.
    __shared__ unsigned int s[4][256];
    (void)acc;
    s[0][threadIdx.x] = ovp; s[1][threadIdx.x] = ovg;
    s[2][threadIdx.x] = bp;  s[3][threadIdx.x] = bg;
    __syncthreads();
    for (int off = 128; off >= 1; off >>= 1) {
        if (threadIdx.x < off) {
            s[0][threadIdx.x] += s[0][threadIdx.x + off];
            s[1][threadIdx.x] += s[1][threadIdx.x + off];
            s[2][threadIdx.x] += s[2][threadIdx.x + off];
            s[3][threadIdx.x] += s[3][threadIdx.x + off];
        }
        __syncthreads();
    }
    if (threadIdx.x == 0) {
        float num   = (float)(s[0][0] + s[1][0]);
        float denom = (float)(s[2][0] + s[3][0]);
        out[0] = denom > 0.0f ? num / denom : 0.0f;
    }
}

extern "C" void kernel_launch(void* const* d_in, const int* in_sizes, int n_in,
                              void* d_out, int out_size, void* d_ws, size_t ws_size,
                              hipStream_t stream) {
    const float* net = (const float*)d_in[0];
    const int*   tgt = (const int*)d_in[1];
    float* out = (float*)d_out;

    unsigned char* bmask = (unsigned char*)d_ws;
    uint4* partials = (uint4*)((char*)d_ws + ((VOL + 15) & ~15));

    const int threads = 256;
    const int blocks  = (VOL + threads - 1) / threads;

    boundary_kernel<<<blocks, threads, 0, stream>>>(net, tgt, bmask);
    count_kernel<<<NBLK, threads, 0, stream>>>(bmask, partials);
    finalize_kernel<<<1, threads, 0, stream>>>(partials, out);
}

// Round 3
// 20.315 us; speedup vs baseline: 55.8276x; 1.1420x over previous
//
#include <hip/hip_runtime.h>

#define D0 128
#define D1 128
#define D2 96
#define VOL (D0 * D1 * D2)      // 1,572,864 voxels
#define NWORDS (VOL / 32)       // 49,152 packed u32 words (3 per column)
#define CB 192                  // count_kernel blocks (CB*CT == NWORDS)
#define CT 256

// ---------------------------------------------------------------------------
// Pass 1: pack occupancy bits. Wave lanes = consecutive linear indices =
// consecutive z within a column (96 % 32 == 0, wave base % 32 == 0, so each
// 32-lane half of the ballot is exactly one packed word; u64 store covers
// words 2k,2k+1 little-endian-correctly).
// ---------------------------------------------------------------------------
__global__ void pack_kernel(const float* __restrict__ net,
                            const int* __restrict__ tgt,
                            unsigned long long* __restrict__ pw,
                            unsigned long long* __restrict__ gw) {
    int idx = blockIdx.x * 256 + threadIdx.x;   // grid is exact: VOL/256 blocks
    bool p = net[idx] > 0.0f;                   // sigmoid(v) > 0.5  <=>  v > 0
    bool g = tgt[idx] != 0;
    unsigned long long mp = __ballot(p);
    unsigned long long mg = __ballot(g);
    if ((threadIdx.x & 63) == 0) {
        int w = idx >> 6;
        pw[w] = mp;
        gw[w] = mg;
    }
}

// ---------------------------------------------------------------------------
// Boundary of one packed word: foreground bit with >=1 background 6-neighbor
// (out-of-volume = background). z-shifts carry across adjacent words.
// ---------------------------------------------------------------------------
__device__ __forceinline__ unsigned int bnd_word(const unsigned int* __restrict__ P,
                                                 int cx, int cy, int wz) {
    if (cx < 0 || cx >= D0 || cy < 0 || cy >= D1) return 0u;
    int base = (cx * D1 + cy) * 3;
    unsigned int w = P[base + wz];
    if (!w) return 0u;
    unsigned int nxm = (cx > 0)      ? P[base - D1 * 3 + wz] : 0u;
    unsigned int nxp = (cx < D0 - 1) ? P[base + D1 * 3 + wz] : 0u;
    unsigned int nym = (cy > 0)      ? P[base - 3 + wz]      : 0u;
    unsigned int nyp = (cy < D1 - 1) ? P[base + 3 + wz]      : 0u;
    unsigned int lo  = (wz > 0)      ? P[base + wz - 1]      : 0u;
    unsigned int hi  = (wz < 2)      ? P[base + wz + 1]      : 0u;
    unsigned int pzm = (w << 1) | (lo >> 31);   // p(z-1) aligned to z
    unsigned int pzp = (w >> 1) | (hi << 31);   // p(z+1) aligned to z
    unsigned int interior = w & nxm & nxp & nym & nyp & pzm & pzp;
    return w & ~interior;
}

// 7-point-cross dilation of bnd(P) at this word (d2 <= 1 test).
__device__ __forceinline__ unsigned int dil_word(const unsigned int* __restrict__ P,
                                                 int cx, int cy, int wz,
                                                 unsigned int B0) {
    unsigned int Bxm = bnd_word(P, cx - 1, cy, wz);
    unsigned int Bxp = bnd_word(P, cx + 1, cy, wz);
    unsigned int Bym = bnd_word(P, cx, cy - 1, wz);
    unsigned int Byp = bnd_word(P, cx, cy + 1, wz);
    unsigned int Bzm = (wz > 0) ? bnd_word(P, cx, cy, wz - 1) : 0u;
    unsigned int Bzp = (wz < 2) ? bnd_word(P, cx, cy, wz + 1) : 0u;
    return B0 | (B0 << 1) | (B0 >> 1) | (Bzm >> 31) | (Bzp << 31)
              | Bxm | Bxp | Bym | Byp;
}

// ---------------------------------------------------------------------------
// Pass 2: boundary + dilation + count, fused, one thread per word.
// ---------------------------------------------------------------------------
__global__ void count_kernel(const unsigned int* __restrict__ pw,
                             const unsigned int* __restrict__ gw,
                             uint4* __restrict__ partials) {
    int w  = blockIdx.x * CT + threadIdx.x;     // exact: CB*CT == NWORDS
    int wz = w % 3;
    int col = w / 3;
    int cy = col % D1;
    int cx = col / D1;

    unsigned int Bp = bnd_word(pw, cx, cy, wz);
    unsigned int Bg = bnd_word(gw, cx, cy, wz);

    unsigned int novp = 0, novg = 0;
    if (Bp) novp = __popc(Bp & dil_word(gw, cx, cy, wz, Bg));
    if (Bg) novg = __popc(Bg & dil_word(pw, cx, cy, wz, Bp));
    unsigned int nbp = __popc(Bp);
    unsigned int nbg = __popc(Bg);

    // packed u64 reduce: fields [0:16)=ovp [16:32)=ovg [32:48)=bp [48:64)=bg
    // per-thread <=32, block sum <= 256*32 = 8192 < 65536: no carry.
    unsigned long long acc = (unsigned long long)novp
                           + ((unsigned long long)novg << 16)
                           + ((unsigned long long)nbp  << 32)
                           + ((unsigned long long)nbg  << 48);
    #pragma unroll
    for (int off = 32; off >= 1; off >>= 1)
        acc += __shfl_down(acc, off, 64);

    __shared__ unsigned long long wsum[4];
    int wave = threadIdx.x >> 6;
    if ((threadIdx.x & 63) == 0) wsum[wave] = acc;
    __syncthreads();
    if (threadIdx.x == 0) {
        unsigned long long t = wsum[0] + wsum[1] + wsum[2] + wsum[3];
        uint4 r;
        r.x = (unsigned int)( t        & 0xFFFF);
        r.y = (unsigned int)((t >> 16) & 0xFFFF);
        r.z = (unsigned int)((t >> 32) & 0xFFFF);
        r.w = (unsigned int)((t >> 48) & 0xFFFF);
        partials[blockIdx.x] = r;
    }
}

// ---------------------------------------------------------------------------
// Pass 3: final scalar.
// ---------------------------------------------------------------------------
__global__ void finalize_kernel(const uint4* __restrict__ partials,
                                float* __restrict__ out) {
    unsigned int ovp = 0, ovg = 0, bp = 0, bg = 0;
    if (threadIdx.x < CB) {
        uint4 v = partials[threadIdx.x];
        ovp = v.x; ovg = v.y; bp = v.z; bg = v.w;
    }
    __shared__ unsigned int s[4][256];
    s[0][threadIdx.x] = ovp; s[1][threadIdx.x] = ovg;
    s[2][threadIdx.x] = bp;  s[3][threadIdx.x] = bg;
    __syncthreads();
    for (int off = 128; off >= 1; off >>= 1) {
        if (threadIdx.x < off) {
            s[0][threadIdx.x] += s[0][threadIdx.x + off];
            s[1][threadIdx.x] += s[1][threadIdx.x + off];
            s[2][threadIdx.x] += s[2][threadIdx.x + off];
            s[3][threadIdx.x] += s[3][threadIdx.x + off];
        }
        __syncthreads();
    }
    if (threadIdx.x == 0) {
        float num   = (float)(s[0][0] + s[1][0]);
        float denom = (float)(s[2][0] + s[3][0]);
        out[0] = denom > 0.0f ? num / denom : 0.0f;
    }
}

extern "C" void kernel_launch(void* const* d_in, const int* in_sizes, int n_in,
                              void* d_out, int out_size, void* d_ws, size_t ws_size,
                              hipStream_t stream) {
    const float* net = (const float*)d_in[0];
    const int*   tgt = (const int*)d_in[1];
    float* out = (float*)d_out;

    // ws layout: pred words | gt words | partials
    unsigned long long* pw = (unsigned long long*)d_ws;                      // 196608 B
    unsigned long long* gw = (unsigned long long*)((char*)d_ws + NWORDS * 4);// 196608 B
    uint4* partials = (uint4*)((char*)d_ws + 2 * NWORDS * 4);                // 3072 B

    pack_kernel<<<VOL / 256, 256, 0, stream>>>(net, tgt, pw, gw);
    count_kernel<<<CB, CT, 0, stream>>>((const unsigned int*)pw,
                                        (const unsigned int*)gw, partials);
    finalize_kernel<<<1, 256, 0, stream>>>(partials, out);
}

// Round 4
// 18.953 us; speedup vs baseline: 59.8384x; 1.0718x over previous
//
#include <hip/hip_runtime.h>

#define D0 128
#define D1 128
#define D2 96
#define TW 8                 // owned tile width in x and y
#define EXT 12               // TW + 2*2 halo (dil needs bnd+-1, bnd needs occ+-2)
#define BND 10               // EXT - 2 (region where boundary words are valid)
#define NBX (D0 / TW)        // 16
#define NBY (D1 / TW)        // 16
#define NBLKS (NBX * NBY)    // 256 partials

// ---------------------------------------------------------------------------
// Fused: pack -> boundary -> 7-point dilation (d2<=1 test) -> per-block counts.
// One block per 8x8 column tile; halo recomputed, no inter-block communication.
// ---------------------------------------------------------------------------
__global__ __launch_bounds__(512) void fused_kernel(const float* __restrict__ net,
                                                    const int* __restrict__ tgt,
                                                    uint4* __restrict__ partials) {
    __shared__ unsigned int pk[2][EXT][EXT][3];   // packed occupancy (p,g)
    __shared__ unsigned int bd[2][BND][BND][3];   // boundary words (p,g)
    __shared__ unsigned long long wsum[8];

    const int tid  = threadIdx.x;
    const int lane = tid & 63;
    const int wid  = tid >> 6;                    // 8 waves
    const int x0   = blockIdx.x * TW;
    const int y0   = blockIdx.y * TW;

    // ---- Phase A: pack 12x12 ext columns (96 z -> 3 words) via ballot.
    // Wave w owns ext-columns [w*18, w*18+18); batch 6 columns so 24 global
    // loads are in flight before the first ballot consumes them (1 block/CU
    // means no TLP -- ILP must hide the load latency).
    for (int c0 = wid * 18; c0 < wid * 18 + 18; c0 += 6) {
        bool pl[6], gl[6], ph[6], gh[6];
        #pragma unroll
        for (int j = 0; j < 6; ++j) {
            int c  = c0 + j;
            int ex = c / EXT, ey = c % EXT;
            int cx = x0 - 2 + ex, cy = y0 - 2 + ey;
            bool in = (cx >= 0 && cx < D0 && cy >= 0 && cy < D1);
            long base = in ? ((long)(cx * D1 + cy)) * D2 : 0;
            bool in2 = in && (lane < 32);
            pl[j] = in  ? (net[base + lane] > 0.0f)      : false;  // z in [0,64)
            gl[j] = in  ? (tgt[base + lane] != 0)        : false;
            ph[j] = in2 ? (net[base + 64 + lane] > 0.0f) : false;  // z in [64,96)
            gh[j] = in2 ? (tgt[base + 64 + lane] != 0)   : false;
        }
        #pragma unroll
        for (int j = 0; j < 6; ++j) {
            unsigned long long mp  = __ballot(pl[j]);
            unsigned long long mg  = __ballot(gl[j]);
            unsigned long long mp2 = __ballot(ph[j]);
            unsigned long long mg2 = __ballot(gh[j]);
            if (lane == 0) {
                int c  = c0 + j;
                int ex = c / EXT, ey = c % EXT;
                pk[0][ex][ey][0] = (unsigned int)mp;
                pk[0][ex][ey][1] = (unsigned int)(mp >> 32);
                pk[0][ex][ey][2] = (unsigned int)mp2;
                pk[1][ex][ey][0] = (unsigned int)mg;
                pk[1][ex][ey][1] = (unsigned int)(mg >> 32);
                pk[1][ex][ey][2] = (unsigned int)mg2;
            }
        }
    }
    __syncthreads();

    // ---- Phase B: boundary words on the 10x10 ext-1 region (both grids).
    // boundary = fg & ~(all 6 neighbors fg), out-of-volume = background
    // (guaranteed by pk==0 outside the volume and z shifts injecting 0).
    for (int it = tid; it < 2 * BND * BND * 3; it += 512) {
        int gr = it / (BND * BND * 3);
        int r  = it % (BND * BND * 3);
        int bx = r / (BND * 3);
        int r2 = r % (BND * 3);
        int by = r2 / 3;
        int wz = r2 % 3;
        int ex = bx + 1, ey = by + 1;
        unsigned int w = pk[gr][ex][ey][wz];
        unsigned int bres = 0u;
        if (w) {
            unsigned int nxm = pk[gr][ex - 1][ey][wz];
            unsigned int nxp = pk[gr][ex + 1][ey][wz];
            unsigned int nym = pk[gr][ex][ey - 1][wz];
            unsigned int nyp = pk[gr][ex][ey + 1][wz];
            unsigned int lo  = (wz > 0) ? pk[gr][ex][ey][wz - 1] : 0u;
            unsigned int hi  = (wz < 2) ? pk[gr][ex][ey][wz + 1] : 0u;
            unsigned int interior = w & nxm & nxp & nym & nyp
                                  & ((w << 1) | (lo >> 31))
                                  & ((w >> 1) | (hi << 31));
            bres = w & ~interior;
        }
        bd[gr][bx][by][wz] = bres;
    }
    __syncthreads();

    // ---- Phase C: dilation + counts on the owned 8x8x3 words.
    unsigned long long acc = 0ull;
    if (tid < TW * TW * 3) {
        int ox = tid / (TW * 3);
        int r  = tid % (TW * 3);
        int oy = r / 3;
        int wz = r % 3;
        int bx = ox + 1, by = oy + 1;   // owned ex = ox+2 -> bd idx ox+1
        unsigned int Bp = bd[0][bx][by][wz];
        unsigned int Bg = bd[1][bx][by][wz];

        unsigned int gzm = (wz > 0) ? bd[1][bx][by][wz - 1] : 0u;
        unsigned int gzp = (wz < 2) ? bd[1][bx][by][wz + 1] : 0u;
        unsigned int dg = Bg | (Bg << 1) | (Bg >> 1) | (gzm >> 31) | (gzp << 31)
                        | bd[1][bx - 1][by][wz] | bd[1][bx + 1][by][wz]
                        | bd[1][bx][by - 1][wz] | bd[1][bx][by + 1][wz];

        unsigned int pzm = (wz > 0) ? bd[0][bx][by][wz - 1] : 0u;
        unsigned int pzp = (wz < 2) ? bd[0][bx][by][wz + 1] : 0u;
        unsigned int dp = Bp | (Bp << 1) | (Bp >> 1) | (pzm >> 31) | (pzp << 31)
                        | bd[0][bx - 1][by][wz] | bd[0][bx + 1][by][wz]
                        | bd[0][bx][by - 1][wz] | bd[0][bx][by + 1][wz];

        unsigned int novp = __popc(Bp & dg);
        unsigned int novg = __popc(Bg & dp);
        unsigned int nbp  = __popc(Bp);
        unsigned int nbg  = __popc(Bg);
        // fields [0:16)=ovp [16:32)=ovg [32:48)=bp [48:64)=bg;
        // block sum <= 192*32 = 6144 < 65536: no cross-field carry.
        acc = (unsigned long long)novp
            + ((unsigned long long)novg << 16)
            + ((unsigned long long)nbp  << 32)
            + ((unsigned long long)nbg  << 48);
    }
    #pragma unroll
    for (int off = 32; off >= 1; off >>= 1)
        acc += __shfl_down(acc, off, 64);
    if (lane == 0) wsum[wid] = acc;
    __syncthreads();
    if (tid == 0) {
        unsigned long long t = 0ull;
        #pragma unroll
        for (int w = 0; w < 8; ++w) t += wsum[w];
        uint4 rr;
        rr.x = (unsigned int)( t        & 0xFFFF);
        rr.y = (unsigned int)((t >> 16) & 0xFFFF);
        rr.z = (unsigned int)((t >> 32) & 0xFFFF);
        rr.w = (unsigned int)((t >> 48) & 0xFFFF);
        partials[blockIdx.y * NBX + blockIdx.x] = rr;
    }
}

// ---------------------------------------------------------------------------
// Finalize: reduce 256 partials, write the scalar.
// ---------------------------------------------------------------------------
__global__ void finalize_kernel(const uint4* __restrict__ partials,
                                float* __restrict__ out) {
    uint4 v = partials[threadIdx.x];
    __shared__ unsigned int s[4][256];
    s[0][threadIdx.x] = v.x; s[1][threadIdx.x] = v.y;
    s[2][threadIdx.x] = v.z; s[3][threadIdx.x] = v.w;
    __syncthreads();
    for (int off = 128; off >= 1; off >>= 1) {
        if (threadIdx.x < (unsigned)off) {
            s[0][threadIdx.x] += s[0][threadIdx.x + off];
            s[1][threadIdx.x] += s[1][threadIdx.x + off];
            s[2][threadIdx.x] += s[2][threadIdx.x + off];
            s[3][threadIdx.x] += s[3][threadIdx.x + off];
        }
        __syncthreads();
    }
    if (threadIdx.x == 0) {
        float num   = (float)(s[0][0] + s[1][0]);
        float denom = (float)(s[2][0] + s[3][0]);
        out[0] = denom > 0.0f ? num / denom : 0.0f;
    }
}

extern "C" void kernel_launch(void* const* d_in, const int* in_sizes, int n_in,
                              void* d_out, int out_size, void* d_ws, size_t ws_size,
                              hipStream_t stream) {
    const float* net = (const float*)d_in[0];
    const int*   tgt = (const int*)d_in[1];
    float* out = (float*)d_out;
    uint4* partials = (uint4*)d_ws;   // 256 * 16 B

    fused_kernel<<<dim3(NBX, NBY), 512, 0, stream>>>(net, tgt, partials);
    finalize_kernel<<<1, NBLKS, 0, stream>>>(partials, out);
}